// Round 4
// baseline (169.830 us; speedup 1.0000x reference)
//
#include <hip/hip_runtime.h>

#define I_DIM 128
#define H_DIM 64
#define BATCH 8
#define SEQ   4096
#define NBIN  (SEQ/2 + 1)     // 2049 bins of the 4096-rfft (K_hat)
#define NBIN2 (SEQ + 1)       // 4097 bins of the 8192-rfft (Kf)

// LDS swizzle on complex (8B) indices. Verified: for radix-8 Stockham at
// s=1,8,64,512 all read/write patterns land at <=4 lanes per bank-pair
// (the ds_*_b64 ideal).
#define SZ(a) ((a) ^ (((a) >> 4) & 15))

// Module-scope device scratch (graph-capture safe, fully rewritten per call).
__device__ float2 g_Hh[I_DIM * NBIN];    // K_hat  [i][k], ~2.1 MB
__device__ float2 g_Kf[I_DIM * NBIN2];   // rfft_8192(K_pad) [i][m], ~4.2 MB

__device__ inline float2 cmul(float2 a, float2 b) {
    return make_float2(a.x * b.x - a.y * b.y, a.x * b.y + a.y * b.x);
}
__device__ inline float2 cadd(float2 a, float2 b) { return make_float2(a.x + b.x, a.y + b.y); }
__device__ inline float2 csub(float2 a, float2 b) { return make_float2(a.x - b.x, a.y - b.y); }

// DFT8 (DIF network), natural-order outputs b[k] = sum_j a[j] W8^{jk}.
// Verified against direct DFT on bins 1,2,3,4.
__device__ inline void dft8(float2 a[8]) {
    const float C = 0.70710678118654752f;
    float2 s0 = cadd(a[0], a[4]), s1 = cadd(a[1], a[5]);
    float2 s2 = cadd(a[2], a[6]), s3 = cadd(a[3], a[7]);
    float2 d0 = csub(a[0], a[4]), d1 = csub(a[1], a[5]);
    float2 d2 = csub(a[2], a[6]), d3 = csub(a[3], a[7]);
    d1 = make_float2(C * (d1.x + d1.y), C * (d1.y - d1.x));   // * W8^1
    d2 = make_float2(d2.y, -d2.x);                            // * W8^2 = -i
    d3 = make_float2(C * (d3.y - d3.x), -C * (d3.x + d3.y));  // * W8^3
    {
        float2 p0 = cadd(s0, s2), p1 = cadd(s1, s3);
        float2 m0 = csub(s0, s2), m1 = csub(s1, s3);
        m1 = make_float2(m1.y, -m1.x);
        a[0] = cadd(p0, p1); a[4] = csub(p0, p1);
        a[2] = cadd(m0, m1); a[6] = csub(m0, m1);
    }
    {
        float2 p0 = cadd(d0, d2), p1 = cadd(d1, d3);
        float2 m0 = csub(d0, d2), m1 = csub(d1, d3);
        m1 = make_float2(m1.y, -m1.x);
        a[1] = cadd(p0, p1); a[5] = csub(p0, p1);
        a[3] = cadd(m0, m1); a[7] = csub(m0, m1);
    }
}

__device__ inline void dft4(float2 a[4]) {
    float2 p0 = cadd(a[0], a[2]), p1 = cadd(a[1], a[3]);
    float2 m0 = csub(a[0], a[2]), m1 = csub(a[1], a[3]);
    m1 = make_float2(m1.y, -m1.x);
    a[0] = cadd(p0, p1); a[2] = csub(p0, p1);
    a[1] = cadd(m0, m1); a[3] = csub(m0, m1);
}

// ---------------------------------------------------------------------------
// One radix-8 Stockham DIF stage, stride S, single-buffer LDS.
// Butterfly u (q = u mod S): reads x[u + j*N/8], computes DFT8, twiddles
// b_k *= w_N^{k(u-q)}, writes y[8u - 7q + k*S]. Generalization of the
// round-3-verified radix-2 form; composition verified by hand at N=8 (4x2).
// Last stage (S == N/8): u==q -> all twiddles 1 (compile-time skipped).
// ---------------------------------------------------------------------------
template <int N, int BPT, int S>
__device__ inline void stage8(float2* __restrict__ lds, int tid) {
    constexpr int NB = N / 8;
    float2 d[BPT][8];
#pragma unroll
    for (int b = 0; b < BPT; ++b) {
        const int u = tid + (b << 8);
#pragma unroll
        for (int j = 0; j < 8; ++j)
            d[b][j] = lds[SZ(u + NB * j)];
    }
    __syncthreads();
#pragma unroll
    for (int b = 0; b < BPT; ++b) {
        const int u = tid + (b << 8);
        const int q = u & (S - 1);
        dft8(d[b]);
        if (S < NB) {
            const float cang = (float)(-6.283185307179586) / (float)N;
            float sn, cs;
            __sincosf(cang * (float)(u - q), &sn, &cs);
            const float2 w = make_float2(cs, sn);
            float2 t = w;
#pragma unroll
            for (int k = 1; k < 8; ++k) {
                d[b][k] = cmul(d[b][k], t);
                if (k < 7) t = cmul(t, w);
            }
        }
        const int base = 8 * u - 7 * q;
#pragma unroll
        for (int k = 0; k < 8; ++k)
            lds[SZ(base + k * S)] = d[b][k];
    }
    __syncthreads();
}

// Final radix-4 stage for N=2048 (S = 512 = N/4 -> q=u, twiddle-free).
__device__ inline void stage4_final_2048(float2* __restrict__ lds, int tid) {
    float2 d[2][4];
#pragma unroll
    for (int b = 0; b < 2; ++b) {
        const int u = tid + (b << 8);
#pragma unroll
        for (int j = 0; j < 4; ++j)
            d[b][j] = lds[SZ(u + 512 * j)];
    }
    __syncthreads();
#pragma unroll
    for (int b = 0; b < 2; ++b) {
        const int u = tid + (b << 8);
        dft4(d[b]);
#pragma unroll
        for (int k = 0; k < 4; ++k)
            lds[SZ(u + 512 * k)] = d[b][k];   // y[4u-3q+k*512] = u+512k
    }
    __syncthreads();
}

// ---------------------------------------------------------------------------
// Kernel 1: K_hat[i,k] (unchanged — verified in rounds 2-3)
// ---------------------------------------------------------------------------
__global__ void khat_kernel(const float* __restrict__ Bm,
                            const float* __restrict__ Cm,
                            const float* __restrict__ Lm,
                            const float* __restrict__ Pm,
                            const float* __restrict__ Qm) {
    int k = blockIdx.x * blockDim.x + threadIdx.x;
    int i = blockIdx.y;
    if (k >= NBIN) return;

    float theta = (float)(6.283185307179586 / (double)SEQ) * (float)k;
    float sn, cs;
    sincosf(theta, &sn, &cs);

    float tr = 1.0f - cs, ti = -sn;
    float br = 1.0f + cs, bi = sn;
    float den = br * br + bi * bi;
    float idn = 1.0f / den;
    float gr = 20.0f * (tr * br + ti * bi) * idn;
    float gi = 20.0f * (ti * br - tr * bi) * idn;
    float cr = 2.0f * br * idn;
    float ci = -2.0f * bi * idn;

    const float* Brow = Bm + i * H_DIM;
    const float* Crow = Cm + i * H_DIM;
    const float* Lrow = Lm + i * H_DIM;
    const float* Prow = Pm + i * H_DIM;
    const float* Qrow = Qm + i * H_DIM;

    float k00r = 0.f, k00i = 0.f, k01r = 0.f, k01i = 0.f;
    float k10r = 0.f, k10i = 0.f, k11r = 0.f, k11i = 0.f;

#pragma unroll 8
    for (int h = 0; h < H_DIM; ++h) {
        float lam = Lrow[h];
        float dr = gr - lam;
        float di = gi;
        float im = 1.0f / (dr * dr + di * di);
        float ivr = dr * im;
        float ivi = -di * im;
        float bv = Brow[h], cv = Crow[h], pv = Prow[h], qv = Qrow[h];
        float cb = cv * bv;
        float cp = cv * pv;
        float qb = qv * bv;
        float qp = qv * pv;
        k00r += cb * ivr; k00i += cb * ivi;
        k01r += cp * ivr; k01i += cp * ivi;
        k10r += qb * ivr; k10i += qb * ivi;
        k11r += qp * ivr; k11i += qp * ivi;
    }

    float t1r = 1.0f + k11r, t1i = k11i;
    float t2r = k01r * t1r - k01i * t1i;
    float t2i = k01r * t1i + k01i * t1r;
    float t3r = t2r * k10r - t2i * k10i;
    float t3i = t2r * k10i + t2i * k10r;
    float nr = k00r - t3r, ni = k00i - t3i;
    float Hr = cr * nr - ci * ni;
    float Hi = cr * ni + ci * nr;
    g_Hh[(size_t)i * NBIN + k] = make_float2(Hr, Hi);
}

// ---------------------------------------------------------------------------
// Kernel 2: K-prep (radix-8 core). Per channel i:
//   icfft_2048 (half-size pack, conj trick) -> v-pack -> cfft_4096 -> untwist
// ---------------------------------------------------------------------------
__global__ __launch_bounds__(256, 4) void kprep_kernel() {
    __shared__ float2 lds[4096];
    const int tid = threadIdx.x;
    const int i = blockIdx.x;
    const float2* Hrow = g_Hh + (size_t)i * NBIN;

    // inverse-rfft half-size pack (store conj for fwd-core icfft)
#pragma unroll
    for (int r = 0; r < 8; ++r) {
        int m = tid + (r << 8);          // m < 2048
        float2 Hm = Hrow[m];
        float2 Hc = Hrow[2048 - m];
        float pr = Hm.x + Hc.x, pi2 = Hm.y - Hc.y;
        float dr = Hm.x - Hc.x, di = Hm.y + Hc.y;
        float sn, cs;
        __sincosf((float)(3.141592653589793 / 2048.0) * (float)m, &sn, &cs);
        float Or = 0.5f * (cs * dr - sn * di);
        float Oi = 0.5f * (sn * dr + cs * di);
        lds[SZ(m)] = make_float2(0.5f * pr - Oi, -(0.5f * pi2 + Or));
    }
    __syncthreads();

    stage8<2048, 1, 1>(lds, tid);
    stage8<2048, 1, 8>(lds, tid);
    stage8<2048, 1, 64>(lds, tid);
    stage4_final_2048(lds, tid);

    // v[n] = K[2n] + j*K[2n+1] = conj(out[n])/2048; zero-pad top half.
    const float s1 = 1.0f / 2048.0f;
#pragma unroll
    for (int r = 0; r < 8; ++r) {
        int n = tid + (r << 8);
        float2 o = lds[SZ(n)];
        lds[SZ(n)]        = make_float2(o.x * s1, -o.y * s1);
        lds[SZ(n + 2048)] = make_float2(0.f, 0.f);
    }
    __syncthreads();

    stage8<4096, 2, 1>(lds, tid);
    stage8<4096, 2, 8>(lds, tid);
    stage8<4096, 2, 64>(lds, tid);
    stage8<4096, 2, 512>(lds, tid);

    // untwist: Kf[m] = E - (j/2) e^{-j*pi*m/4096} (Zv[m]-conj(Zv[4096-m]))
    float2* Kfrow = g_Kf + (size_t)i * NBIN2;
#pragma unroll
    for (int r = 0; r < 17; ++r) {
        int m = tid + (r << 8);
        if (m <= 4096) {
            float2 Zq = lds[SZ(m & 4095)];
            float2 Zr = lds[SZ((4096 - m) & 4095)];
            float sn, cs;
            __sincosf((float)(-3.141592653589793 / 4096.0) * (float)m, &sn, &cs);
            float pr = Zq.x + Zr.x, pi2 = Zq.y - Zr.y;
            float dr = Zq.x - Zr.x, di = Zq.y + Zr.y;
            float jt_r = -sn * dr - cs * di;
            float jt_i =  cs * dr - sn * di;
            Kfrow[m] = make_float2(0.5f * (pr - jt_r), 0.5f * (pi2 - jt_i));
        }
    }
}

// ---------------------------------------------------------------------------
// Kernel 3: FFT convolution, one block per (b,i), radix-8 single-buffer.
//   pack -> cfft_4096 -> combine (untwist * Kf retwist, own-slot pairs)
//   -> icfft_4096 (conj trick) -> unpack.
// ---------------------------------------------------------------------------
__device__ inline void combine_pair(float2* __restrict__ lds,
                                    const float2* __restrict__ Kfrow,
                                    int m, bool write_partner) {
    float2 Zq = lds[SZ(m & 4095)];
    float2 Zr = lds[SZ((4096 - m) & 4095)];
    float sn, cs;
    __sincosf((float)(-3.141592653589793 / 4096.0) * (float)m, &sn, &cs);
    float pr = Zq.x + Zr.x, pi2 = Zq.y - Zr.y;
    float dr = Zq.x - Zr.x, di = Zq.y + Zr.y;
    float jt_r = -sn * dr - cs * di;
    float jt_i =  cs * dr - sn * di;
    float2 Xm  = make_float2(0.5f * (pr - jt_r),  0.5f * ( pi2 - jt_i));
    float2 Xm2 = make_float2(0.5f * (pr + jt_r),  0.5f * (-pi2 - jt_i));
    float2 Ym  = cmul(Xm,  Kfrow[m]);
    float2 Ym2 = cmul(Xm2, Kfrow[4096 - m]);
    float qr = Ym.x + Ym2.x, qi = Ym.y - Ym2.y;
    float er = Ym.x - Ym2.x, ei = Ym.y + Ym2.y;
    float gr2 = sn * er - cs * ei;
    float gi2 = sn * ei + cs * er;
    // store conj(Zy) for the conj-trick inverse
    lds[SZ(m & 4095)] = make_float2(0.5f * (qr + gr2), -0.5f * (qi + gi2));
    if (write_partner)
        lds[SZ(4096 - m)] = make_float2(0.5f * (qr - gr2), 0.5f * (qi - gi2));
}

__global__ __launch_bounds__(256, 4) void fftconv_kernel(const float* __restrict__ x,
                                                         float* __restrict__ y) {
    __shared__ float2 lds[4096];
    const int tid = threadIdx.x;
    const int b = blockIdx.x & 7;
    const int i = blockIdx.x >> 3;

    const float* xb = x + (size_t)b * SEQ * I_DIM + i;
#pragma unroll
    for (int r = 0; r < 8; ++r) {
        int n = tid + (r << 8);          // n < 2048
        float re = xb[(size_t)(2 * n) * I_DIM];
        float im = xb[(size_t)(2 * n + 1) * I_DIM];
        lds[SZ(n)]        = make_float2(re, im);
        lds[SZ(n + 2048)] = make_float2(0.f, 0.f);
    }
    __syncthreads();

    stage8<4096, 2, 1>(lds, tid);
    stage8<4096, 2, 8>(lds, tid);
    stage8<4096, 2, 64>(lds, tid);
    stage8<4096, 2, 512>(lds, tid);

    // combine: thread owns slot-pairs {m, 4096-m}; no internal barrier needed.
    const float2* Kfrow = g_Kf + (size_t)i * NBIN2;
#pragma unroll
    for (int r = 0; r < 8; ++r) {
        int m = tid + (r << 8);          // 0..2047
        combine_pair(lds, Kfrow, m, m != 0);
    }
    if (tid == 0)
        combine_pair(lds, Kfrow, 2048, false);   // self-paired Nyquist bin
    __syncthreads();

    stage8<4096, 2, 1>(lds, tid);
    stage8<4096, 2, 8>(lds, tid);
    stage8<4096, 2, 64>(lds, tid);
    stage8<4096, 2, 512>(lds, tid);

    const float inv = 1.0f / 4096.0f;
    float* yb = y + (size_t)b * SEQ * I_DIM + i;
#pragma unroll
    for (int r = 0; r < 8; ++r) {
        int n = tid + (r << 8);          // n < 2048
        float2 v = lds[SZ(n)];
        yb[(size_t)(2 * n) * I_DIM]     = v.x * inv;
        yb[(size_t)(2 * n + 1) * I_DIM] = -v.y * inv;
    }
}

// ---------------------------------------------------------------------------
extern "C" void kernel_launch(void* const* d_in, const int* in_sizes, int n_in,
                              void* d_out, int out_size, void* d_ws, size_t ws_size,
                              hipStream_t stream) {
    const float* x  = (const float*)d_in[0];
    const float* Bm = (const float*)d_in[1];
    const float* Cm = (const float*)d_in[2];
    const float* Lm = (const float*)d_in[3];
    const float* Pm = (const float*)d_in[4];
    const float* Qm = (const float*)d_in[5];
    float* out = (float*)d_out;

    khat_kernel<<<dim3((NBIN + 255) / 256, I_DIM), 256, 0, stream>>>(Bm, Cm, Lm, Pm, Qm);
    kprep_kernel<<<I_DIM, 256, 0, stream>>>();
    fftconv_kernel<<<BATCH * I_DIM, 256, 0, stream>>>(x, out);
}

// Round 5
// 91.389 us; speedup vs baseline: 1.8583x; 1.8583x over previous
//
#include <hip/hip_runtime.h>

#define I_DIM 128
#define H_DIM 64
#define BATCH 8
#define SEQ   4096
#define NBIN  (SEQ/2 + 1)     // 2049 bins of the 4096-rfft (K_hat)
#define NBIN2 (SEQ + 1)       // 4097 bins of the 8192-rfft (Kf)

// LDS swizzle on complex (8B) indices: spreads strided Stockham writes
// across bank-pairs (verified: all stage patterns reach the 4-lanes/bank-pair
// b64 minimum).
#define SZ(a) ((a) ^ (((a) >> 4) & 15))

// Module-scope device scratch (graph-capture safe, fully rewritten per call).
__device__ float2 g_Hh[I_DIM * NBIN];    // K_hat  [i][k], ~2.1 MB
__device__ float2 g_Kf[I_DIM * NBIN2];   // rfft_8192(K_pad) [i][m], ~4.2 MB

__device__ inline float2 cmul(float2 a, float2 b) {
    return make_float2(a.x * b.x - a.y * b.y, a.x * b.y + a.y * b.x);
}
__device__ inline float2 cadd(float2 a, float2 b) { return make_float2(a.x + b.x, a.y + b.y); }
__device__ inline float2 csub(float2 a, float2 b) { return make_float2(a.x - b.x, a.y - b.y); }

// DFT8 (DIF network), natural-order outputs b[k] = sum_j a[j] W8^{jk}.
__device__ inline void dft8(float2 a[8]) {
    const float C = 0.70710678118654752f;
    float2 s0 = cadd(a[0], a[4]), s1 = cadd(a[1], a[5]);
    float2 s2 = cadd(a[2], a[6]), s3 = cadd(a[3], a[7]);
    float2 d0 = csub(a[0], a[4]), d1 = csub(a[1], a[5]);
    float2 d2 = csub(a[2], a[6]), d3 = csub(a[3], a[7]);
    d1 = make_float2(C * (d1.x + d1.y), C * (d1.y - d1.x));   // * W8^1
    d2 = make_float2(d2.y, -d2.x);                            // * W8^2 = -i
    d3 = make_float2(C * (d3.y - d3.x), -C * (d3.x + d3.y));  // * W8^3
    {
        float2 p0 = cadd(s0, s2), p1 = cadd(s1, s3);
        float2 m0 = csub(s0, s2), m1 = csub(s1, s3);
        m1 = make_float2(m1.y, -m1.x);
        a[0] = cadd(p0, p1); a[4] = csub(p0, p1);
        a[2] = cadd(m0, m1); a[6] = csub(m0, m1);
    }
    {
        float2 p0 = cadd(d0, d2), p1 = cadd(d1, d3);
        float2 m0 = csub(d0, d2), m1 = csub(d1, d3);
        m1 = make_float2(m1.y, -m1.x);
        a[1] = cadd(p0, p1); a[5] = csub(p0, p1);
        a[3] = cadd(m0, m1); a[7] = csub(m0, m1);
    }
}

__device__ inline void dft4(float2 a[4]) {
    float2 p0 = cadd(a[0], a[2]), p1 = cadd(a[1], a[3]);
    float2 m0 = csub(a[0], a[2]), m1 = csub(a[1], a[3]);
    m1 = make_float2(m1.y, -m1.x);
    a[0] = cadd(p0, p1); a[2] = csub(p0, p1);
    a[1] = cadd(m0, m1); a[3] = csub(m0, m1);
}

// ---------------------------------------------------------------------------
// Radix-8 Stockham DIF stage, stride S, single-buffer LDS, NT threads.
// Butterfly u (q = u mod S): reads x[u + j*N/8], DFT8, b_k *= w_N^{k(u-q)},
// writes y[8u - 7q + k*S]. Empirically verified (rounds 3-4 passed).
// S == N/8 (last stage) is twiddle-free (compile-time skipped).
// ---------------------------------------------------------------------------
template <int N, int S, int NT>
__device__ inline void stage8(float2* __restrict__ lds, int tid) {
    constexpr int NB = N / 8;
    constexpr int ITER = (NB + NT - 1) / NT;
    const bool act = (NB >= NT) || (tid < NB);
    float2 d[ITER][8];
#pragma unroll
    for (int b = 0; b < ITER; ++b) {
        const int u = tid + b * NT;
        if (act) {
#pragma unroll
            for (int j = 0; j < 8; ++j)
                d[b][j] = lds[SZ(u + NB * j)];
        }
    }
    __syncthreads();
#pragma unroll
    for (int b = 0; b < ITER; ++b) {
        const int u = tid + b * NT;
        if (act) {
            const int q = u & (S - 1);
            dft8(d[b]);
            if (S < NB) {
                const float cang = (float)(-6.283185307179586) / (float)N;
                float sn, cs;
                __sincosf(cang * (float)(u - q), &sn, &cs);
                const float2 w = make_float2(cs, sn);
                float2 t = w;
#pragma unroll
                for (int k = 1; k < 8; ++k) {
                    d[b][k] = cmul(d[b][k], t);
                    if (k < 7) t = cmul(t, w);
                }
            }
            const int base = 8 * u - 7 * q;
#pragma unroll
            for (int k = 0; k < 8; ++k)
                lds[SZ(base + k * S)] = d[b][k];
        }
    }
    __syncthreads();
}

// Radix-4 Stockham stage (same formula with R=4): y[4u-3q+kS], w_N^{k(u-q)}.
// Mixed-radix composition hand-verified at N=8 (4x2).
template <int N, int S, int NT>
__device__ inline void stage4(float2* __restrict__ lds, int tid) {
    constexpr int NB = N / 4;
    constexpr int ITER = (NB + NT - 1) / NT;
    const bool act = (NB >= NT) || (tid < NB);
    float2 d[ITER][4];
#pragma unroll
    for (int b = 0; b < ITER; ++b) {
        const int u = tid + b * NT;
        if (act) {
#pragma unroll
            for (int j = 0; j < 4; ++j)
                d[b][j] = lds[SZ(u + NB * j)];
        }
    }
    __syncthreads();
#pragma unroll
    for (int b = 0; b < ITER; ++b) {
        const int u = tid + b * NT;
        if (act) {
            const int q = u & (S - 1);
            dft4(d[b]);
            if (S < NB) {
                const float cang = (float)(-6.283185307179586) / (float)N;
                float sn, cs;
                __sincosf(cang * (float)(u - q), &sn, &cs);
                const float2 w = make_float2(cs, sn);
                float2 t = w;
#pragma unroll
                for (int k = 1; k < 4; ++k) {
                    d[b][k] = cmul(d[b][k], t);
                    if (k < 3) t = cmul(t, w);
                }
            }
            const int base = 4 * u - 3 * q;
#pragma unroll
            for (int k = 0; k < 4; ++k)
                lds[SZ(base + k * S)] = d[b][k];
        }
    }
    __syncthreads();
}

// ---------------------------------------------------------------------------
// Kernel 1: K_hat[i,k] (unchanged — verified rounds 2-4)
// ---------------------------------------------------------------------------
__global__ void khat_kernel(const float* __restrict__ Bm,
                            const float* __restrict__ Cm,
                            const float* __restrict__ Lm,
                            const float* __restrict__ Pm,
                            const float* __restrict__ Qm) {
    int k = blockIdx.x * blockDim.x + threadIdx.x;
    int i = blockIdx.y;
    if (k >= NBIN) return;

    float theta = (float)(6.283185307179586 / (double)SEQ) * (float)k;
    float sn, cs;
    sincosf(theta, &sn, &cs);

    float tr = 1.0f - cs, ti = -sn;
    float br = 1.0f + cs, bi = sn;
    float den = br * br + bi * bi;
    float idn = 1.0f / den;
    float gr = 20.0f * (tr * br + ti * bi) * idn;
    float gi = 20.0f * (ti * br - tr * bi) * idn;
    float cr = 2.0f * br * idn;
    float ci = -2.0f * bi * idn;

    const float* Brow = Bm + i * H_DIM;
    const float* Crow = Cm + i * H_DIM;
    const float* Lrow = Lm + i * H_DIM;
    const float* Prow = Pm + i * H_DIM;
    const float* Qrow = Qm + i * H_DIM;

    float k00r = 0.f, k00i = 0.f, k01r = 0.f, k01i = 0.f;
    float k10r = 0.f, k10i = 0.f, k11r = 0.f, k11i = 0.f;

#pragma unroll 8
    for (int h = 0; h < H_DIM; ++h) {
        float lam = Lrow[h];
        float dr = gr - lam;
        float di = gi;
        float im = 1.0f / (dr * dr + di * di);
        float ivr = dr * im;
        float ivi = -di * im;
        float bv = Brow[h], cv = Crow[h], pv = Prow[h], qv = Qrow[h];
        float cb = cv * bv;
        float cp = cv * pv;
        float qb = qv * bv;
        float qp = qv * pv;
        k00r += cb * ivr; k00i += cb * ivi;
        k01r += cp * ivr; k01i += cp * ivi;
        k10r += qb * ivr; k10i += qb * ivi;
        k11r += qp * ivr; k11i += qp * ivi;
    }

    float t1r = 1.0f + k11r, t1i = k11i;
    float t2r = k01r * t1r - k01i * t1i;
    float t2i = k01r * t1i + k01i * t1r;
    float t3r = t2r * k10r - t2i * k10i;
    float t3i = t2r * k10i + t2i * k10r;
    float nr = k00r - t3r, ni = k00i - t3i;
    float Hr = cr * nr - ci * ni;
    float Hi = cr * ni + ci * nr;
    g_Hh[(size_t)i * NBIN + k] = make_float2(Hr, Hi);
}

// ---------------------------------------------------------------------------
// Kernel 2: K-prep, 512 threads. Per channel i:
//   icfft_2048 (half-size pack, conj trick; radix 4*8*8*8)
//   -> v-pack -> cfft_4096 (radix 8^4) -> untwist -> Kf
// ---------------------------------------------------------------------------
__global__ __launch_bounds__(512) void kprep_kernel() {
    __shared__ float2 lds[4096];
    const int tid = threadIdx.x;
    const int i = blockIdx.x;
    const float2* Hrow = g_Hh + (size_t)i * NBIN;

    // inverse-rfft half-size pack (store conj for fwd-core icfft)
#pragma unroll
    for (int r = 0; r < 4; ++r) {
        int m = tid + (r << 9);          // m < 2048
        float2 Hm = Hrow[m];
        float2 Hc = Hrow[2048 - m];
        float pr = Hm.x + Hc.x, pi2 = Hm.y - Hc.y;
        float dr = Hm.x - Hc.x, di = Hm.y + Hc.y;
        float sn, cs;
        __sincosf((float)(3.141592653589793 / 2048.0) * (float)m, &sn, &cs);
        float Or = 0.5f * (cs * dr - sn * di);
        float Oi = 0.5f * (sn * dr + cs * di);
        lds[SZ(m)] = make_float2(0.5f * pr - Oi, -(0.5f * pi2 + Or));
    }
    __syncthreads();

    stage4<2048, 1,   512>(lds, tid);
    stage8<2048, 4,   512>(lds, tid);
    stage8<2048, 32,  512>(lds, tid);
    stage8<2048, 256, 512>(lds, tid);    // S == N/8: twiddle-free

    // v[n] = K[2n] + j*K[2n+1] = conj(out[n])/2048; zero-pad top half.
    const float s1 = 1.0f / 2048.0f;
#pragma unroll
    for (int r = 0; r < 4; ++r) {
        int n = tid + (r << 9);
        float2 o = lds[SZ(n)];
        lds[SZ(n)]        = make_float2(o.x * s1, -o.y * s1);
        lds[SZ(n + 2048)] = make_float2(0.f, 0.f);
    }
    __syncthreads();

    stage8<4096, 1,   512>(lds, tid);
    stage8<4096, 8,   512>(lds, tid);
    stage8<4096, 64,  512>(lds, tid);
    stage8<4096, 512, 512>(lds, tid);

    // untwist: Kf[m] = E - (j/2) e^{-j*pi*m/4096} (Zv[m]-conj(Zv[4096-m]))
    float2* Kfrow = g_Kf + (size_t)i * NBIN2;
#pragma unroll
    for (int r = 0; r < 9; ++r) {
        int m = tid + (r << 9);
        if (m <= 4096) {
            float2 Zq = lds[SZ(m & 4095)];
            float2 Zr = lds[SZ((4096 - m) & 4095)];
            float sn, cs;
            __sincosf((float)(-3.141592653589793 / 4096.0) * (float)m, &sn, &cs);
            float pr = Zq.x + Zr.x, pi2 = Zq.y - Zr.y;
            float dr = Zq.x - Zr.x, di = Zq.y + Zr.y;
            float jt_r = -sn * dr - cs * di;
            float jt_i =  cs * dr - sn * di;
            Kfrow[m] = make_float2(0.5f * (pr - jt_r), 0.5f * (pi2 - jt_i));
        }
    }
}

// ---------------------------------------------------------------------------
// Kernel 3: FFT convolution, one block per (b,i), 512 threads, radix-8
// single-buffer. pack -> cfft_4096 -> combine -> icfft_4096 -> unpack.
// ---------------------------------------------------------------------------
__device__ inline void combine_pair(float2* __restrict__ lds,
                                    const float2* __restrict__ Kfrow,
                                    int m, bool write_partner) {
    float2 Zq = lds[SZ(m & 4095)];
    float2 Zr = lds[SZ((4096 - m) & 4095)];
    float sn, cs;
    __sincosf((float)(-3.141592653589793 / 4096.0) * (float)m, &sn, &cs);
    float pr = Zq.x + Zr.x, pi2 = Zq.y - Zr.y;
    float dr = Zq.x - Zr.x, di = Zq.y + Zr.y;
    float jt_r = -sn * dr - cs * di;
    float jt_i =  cs * dr - sn * di;
    float2 Xm  = make_float2(0.5f * (pr - jt_r),  0.5f * ( pi2 - jt_i));
    float2 Xm2 = make_float2(0.5f * (pr + jt_r),  0.5f * (-pi2 - jt_i));
    float2 Ym  = cmul(Xm,  Kfrow[m]);
    float2 Ym2 = cmul(Xm2, Kfrow[4096 - m]);
    float qr = Ym.x + Ym2.x, qi = Ym.y - Ym2.y;
    float er = Ym.x - Ym2.x, ei = Ym.y + Ym2.y;
    float gr2 = sn * er - cs * ei;
    float gi2 = sn * ei + cs * er;
    // store conj(Zy) for the conj-trick inverse
    lds[SZ(m & 4095)] = make_float2(0.5f * (qr + gr2), -0.5f * (qi + gi2));
    if (write_partner)
        lds[SZ(4096 - m)] = make_float2(0.5f * (qr - gr2), 0.5f * (qi - gi2));
}

__global__ __launch_bounds__(512) void fftconv_kernel(const float* __restrict__ x,
                                                      float* __restrict__ y) {
    __shared__ float2 lds[4096];
    const int tid = threadIdx.x;
    const int b = blockIdx.x & 7;
    const int i = blockIdx.x >> 3;

    const float* xb = x + (size_t)b * SEQ * I_DIM + i;
#pragma unroll
    for (int r = 0; r < 4; ++r) {
        int n = tid + (r << 9);          // n < 2048
        float re = xb[(size_t)(2 * n) * I_DIM];
        float im = xb[(size_t)(2 * n + 1) * I_DIM];
        lds[SZ(n)]        = make_float2(re, im);
        lds[SZ(n + 2048)] = make_float2(0.f, 0.f);
    }
    __syncthreads();

    stage8<4096, 1,   512>(lds, tid);
    stage8<4096, 8,   512>(lds, tid);
    stage8<4096, 64,  512>(lds, tid);
    stage8<4096, 512, 512>(lds, tid);

    // combine: thread owns slot-pairs {m, 4096-m}; no internal barrier.
    const float2* Kfrow = g_Kf + (size_t)i * NBIN2;
#pragma unroll
    for (int r = 0; r < 4; ++r) {
        int m = tid + (r << 9);          // 0..2047
        combine_pair(lds, Kfrow, m, m != 0);
    }
    if (tid == 0)
        combine_pair(lds, Kfrow, 2048, false);   // self-paired Nyquist bin
    __syncthreads();

    stage8<4096, 1,   512>(lds, tid);
    stage8<4096, 8,   512>(lds, tid);
    stage8<4096, 64,  512>(lds, tid);
    stage8<4096, 512, 512>(lds, tid);

    const float inv = 1.0f / 4096.0f;
    float* yb = y + (size_t)b * SEQ * I_DIM + i;
#pragma unroll
    for (int r = 0; r < 4; ++r) {
        int n = tid + (r << 9);          // n < 2048
        float2 v = lds[SZ(n)];
        yb[(size_t)(2 * n) * I_DIM]     = v.x * inv;
        yb[(size_t)(2 * n + 1) * I_DIM] = -v.y * inv;
    }
}

// ---------------------------------------------------------------------------
extern "C" void kernel_launch(void* const* d_in, const int* in_sizes, int n_in,
                              void* d_out, int out_size, void* d_ws, size_t ws_size,
                              hipStream_t stream) {
    const float* x  = (const float*)d_in[0];
    const float* Bm = (const float*)d_in[1];
    const float* Cm = (const float*)d_in[2];
    const float* Lm = (const float*)d_in[3];
    const float* Pm = (const float*)d_in[4];
    const float* Qm = (const float*)d_in[5];
    float* out = (float*)d_out;

    khat_kernel<<<dim3((NBIN + 255) / 256, I_DIM), 256, 0, stream>>>(Bm, Cm, Lm, Pm, Qm);
    kprep_kernel<<<I_DIM, 512, 0, stream>>>();
    fftconv_kernel<<<BATCH * I_DIM, 512, 0, stream>>>(x, out);
}